// Round 2
// 5284.698 us; speedup vs baseline: 1.3962x; 1.3962x over previous
//
#include <hip/hip_runtime.h>
#include <math.h>

#define NSW 12  // one-sided works on implicit X^2: extra sweeps vs the two-sided kernel

__device__ __forceinline__ float bperm_f(int addr4, float v) {
    return __int_as_float(__builtin_amdgcn_ds_bpermute(addr4, __float_as_int(v)));
}

// One-sided (Hestenes) Jacobi: lane l owns column l of W = X * J_accum.
// Pairing: circle-method tournament (the ordering verified to converge on this
// data by the two-sided R0 kernel). No LDS, no barriers in the rotation loop.
// Eigenvalues: lambda_l^2 = ||w_l||^2 = alpha_l; eigvecs: w_l / lambda_l.
// logm = sum_l h_l * w_l w_l^T,  h_l = 0.5 * ln(alpha_l) / alpha_l.
__global__ __launch_bounds__(64, 2) void logeig_kernel(
    const float* __restrict__ Xg, float* __restrict__ out)
{
    __shared__ __align__(16) float W[64 * 68];  // epilogue transpose buffer
    __shared__ float hlds[64];

    const int lane = threadIdx.x;
    const int b = blockIdx.x;

    // ---- load column `lane` of X; X is symmetric so read ROW `lane` (float4) ----
    float x[64];
    {
        const float4* __restrict__ Xb4 = (const float4*)(Xg + (size_t)b * 4096);
        #pragma unroll
        for (int m = 0; m < 16; ++m) {
            float4 v = Xb4[lane * 16 + m];
            x[4 * m + 0] = v.x; x[4 * m + 1] = v.y;
            x[4 * m + 2] = v.z; x[4 * m + 3] = v.w;
        }
    }

    // ---- initial squared norm alpha ----
    float d;
    {
        float a0 = 0.f, a1 = 0.f, a2 = 0.f, a3 = 0.f;
        #pragma unroll
        for (int k = 0; k < 64; k += 4) {
            a0 = fmaf(x[k + 0], x[k + 0], a0);
            a1 = fmaf(x[k + 1], x[k + 1], a1);
            a2 = fmaf(x[k + 2], x[k + 2], a2);
            a3 = fmaf(x[k + 3], x[k + 3], a3);
        }
        d = (a0 + a1) + (a2 + a3);
    }

    // ---- tournament state ----
    // labels 0..62 for lanes 1..63; lane 0 is the fixed player.
    // round r: label m plays m' = (r - m) mod 63 (plays lane 0 if m'==m);
    // lane 0 plays label m0 = 32*r mod 63. Both maintained incrementally.
    const int m  = lane - 1;                       // -1 for lane 0 (unused there)
    int pm = (lane == 0) ? 0 : ((63 - m) % 63);    // (r - m) mod 63 at r=0
    int p0 = 0;                                    // 32*r mod 63

    for (int sweep = 0; sweep < NSW; ++sweep) {
        for (int r = 0; r < 63; ++r) {
            const int prt  = (lane == 0) ? (p0 + 1)
                                         : ((pm == m) ? 0 : (pm + 1));
            const int prt4 = prt << 2;

            // fetch partner column (permutation bpermute) + Gram dot product
            float xp[64];
            float g0 = 0.f, g1 = 0.f, g2 = 0.f, g3 = 0.f;
            #pragma unroll
            for (int k = 0; k < 64; k += 4) {
                xp[k + 0] = bperm_f(prt4, x[k + 0]);
                xp[k + 1] = bperm_f(prt4, x[k + 1]);
                xp[k + 2] = bperm_f(prt4, x[k + 2]);
                xp[k + 3] = bperm_f(prt4, x[k + 3]);
                g0 = fmaf(x[k + 0], xp[k + 0], g0);
                g1 = fmaf(x[k + 1], xp[k + 1], g1);
                g2 = fmaf(x[k + 2], xp[k + 2], g2);
                g3 = fmaf(x[k + 3], xp[k + 3], g3);
            }
            const float g  = (g0 + g1) + (g2 + g3);   // gamma: bit-identical on both lanes
            const float dq = bperm_f(prt4, d);        // partner's squared norm
            const bool  lo = lane < prt;
            const bool  ok = fabsf(g) > 1e-30f;

            // angle from the LO lane's perspective (identical arithmetic on both):
            // zeta = (beta - alpha) / (2 gamma), t = sign(zeta)/(|zeta|+sqrt(1+zeta^2))
            const float num  = lo ? (dq - d) : (d - dq);
            const float zeta = num / (2.f * g);
            const float az   = fabsf(zeta);
            float tl = 1.f / (az + sqrtf(fmaf(az, az, 1.f)));
            tl = (zeta >= 0.f) ? tl : -tl;            // lo-side t
            float tn = lo ? tl : -tl;                 // own signed t (hi negates)
            tn = ok ? tn : 0.f;
            const float c = rsqrtf(fmaf(tn, tn, 1.f));
            const float s = c * tn;

            // Rutishauser norm update: alpha' = alpha - t_own * gamma
            d = fmaf(-tn, g, d);

            // column update: u' = c*u - s_own*u_partner (exact pair-consistent)
            #pragma unroll
            for (int k = 0; k < 64; ++k)
                x[k] = fmaf(-s, xp[k], c * x[k]);

            // advance tournament state
            pm = (pm + 1 == 63) ? 0 : (pm + 1);
            p0 += 32; if (p0 >= 63) p0 -= 63;
        }

        // sweep boundary: resync squared norm (kills Rutishauser drift)
        float a0 = 0.f, a1 = 0.f, a2 = 0.f, a3 = 0.f;
        #pragma unroll
        for (int k = 0; k < 64; k += 4) {
            a0 = fmaf(x[k + 0], x[k + 0], a0);
            a1 = fmaf(x[k + 1], x[k + 1], a1);
            a2 = fmaf(x[k + 2], x[k + 2], a2);
            a3 = fmaf(x[k + 3], x[k + 3], a3);
        }
        d = (a0 + a1) + (a2 + a3);
    }

    // ---- epilogue: out = sum_l h_l * w_l w_l^T ----
    const float alpha = fmaxf(d, 1e-12f);
    const float h = 0.5f * logf(alpha) / alpha;
    hlds[lane] = h;
    #pragma unroll
    for (int k = 0; k < 64; ++k) W[k * 68 + lane] = x[k];   // W[k][l] = w_l[k]
    __syncthreads();

    // register row j = lane, scaled: rreg[l] = h_l * w_l[lane]
    float rreg[64];
    #pragma unroll
    for (int l = 0; l < 64; ++l) rreg[l] = W[lane * 68 + l] * hlds[l];

    // out[i][lane] = sum_l w_l[i] * rreg[l]  (uniform b128 broadcast rows, coalesced stores)
    float* __restrict__ outb = out + (size_t)b * 4096;
    for (int i = 0; i < 64; ++i) {
        float acc0 = 0.f, acc1 = 0.f;
        #pragma unroll
        for (int l4 = 0; l4 < 16; ++l4) {
            const float4 w4 = *(const float4*)&W[i * 68 + l4 * 4];
            acc0 = fmaf(w4.x, rreg[4 * l4 + 0], acc0);
            acc1 = fmaf(w4.y, rreg[4 * l4 + 1], acc1);
            acc0 = fmaf(w4.z, rreg[4 * l4 + 2], acc0);
            acc1 = fmaf(w4.w, rreg[4 * l4 + 3], acc1);
        }
        outb[i * 64 + lane] = acc0 + acc1;
    }
}

extern "C" void kernel_launch(void* const* d_in, const int* in_sizes, int n_in,
                              void* d_out, int out_size, void* d_ws, size_t ws_size,
                              hipStream_t stream)
{
    const float* X = (const float*)d_in[0];
    float* out = (float*)d_out;
    const int B = in_sizes[0] / 4096;   // 8192 matrices of 64x64 fp32
    logeig_kernel<<<dim3(B), dim3(64), 0, stream>>>(X, out);
}